// Round 1
// baseline (176.293 us; speedup 1.0000x reference)
//
#include <hip/hip_runtime.h>
#include <hip/hip_bf16.h>
#include <stdint.h>

#define NJ 21
#define ROWS_TOTAL (16384*21)      /* 344064 */
#define TILE_ROWS 63               /* 3 batches per wave */
#define NTILES ((ROWS_TOTAL + TILE_ROWS - 1)/TILE_ROWS)  /* 5462 */

typedef __attribute__((ext_vector_type(8))) short short8;
typedef __attribute__((ext_vector_type(4))) float f32x4;

__device__ __forceinline__ uint16_t f2bf(float f){
  union{float f; uint32_t u;} v; v.f = f;
  uint32_t r = v.u + 0x7FFF + ((v.u>>16)&1);
  return (uint16_t)(r>>16);
}
__device__ __forceinline__ float bf2f(uint16_t b){
  union{uint32_t u; float f;} v; v.u = ((uint32_t)b)<<16;
  return v.f;
}

/* Pack W1 / W2a / W2b (f32 -> bf16) into MFMA B-fragment-linear order:
   buf[(((ks*8)+nt)*64 + lane)*8 + e] = W[k=32ks+8*(lane>>4)+e][n=16nt+(lane&15)] */
__global__ void pack_kernel(const float* __restrict__ W1, const float* __restrict__ W2,
                            uint16_t* __restrict__ w1p, uint16_t* __restrict__ w2ap,
                            uint16_t* __restrict__ w2bp){
  int idx = blockIdx.x*256 + threadIdx.x;       /* 0..49151 */
  int which = idx >> 14;
  int sub = idx & 16383;
  int e = sub & 7, lane = (sub>>3)&63, nt = (sub>>9)&7, ks = sub>>12;
  int k = 32*ks + 8*(lane>>4) + e;
  int n = 16*nt + (lane&15);
  if (which==0)      w1p[sub]  = f2bf(W1[k*128+n]);
  else if (which==1) w2ap[sub] = f2bf(W2[k*128+n]);
  else               w2bp[sub] = f2bf(W2[(k+128)*128+n]);
}

/* w_s = W1 @ a1, w_t = W1 @ a2 (associativity: s = x @ (W1@a1)) */
__global__ void wst_kernel(const float* __restrict__ W1, const float* __restrict__ a,
                           float* __restrict__ wsv, float* __restrict__ wtv){
  int f = threadIdx.x;  /* 128 threads */
  float s=0.f, t=0.f;
  for (int p=0; p<128; ++p){ float w = W1[f*128+p]; s += w*a[p]; t += w*a[128+p]; }
  wsv[f]=s; wtv[f]=t;
}

__global__ __launch_bounds__(64) void camgat_kernel(
    const float* __restrict__ x, const float* __restrict__ cam,
    const float* __restrict__ bias,
    const uint16_t* __restrict__ w1p, const uint16_t* __restrict__ w2ap,
    const uint16_t* __restrict__ w2bp,
    const float* __restrict__ wsv, const float* __restrict__ wtv,
    float* __restrict__ out)
{
  __shared__ uint16_t sHT[128*64];      /* h_T[c][r]; reused as X_AGG[64][128] */
  __shared__ uint16_t sALPHA[64*64];    /* block-diag alpha, row-major */
  __shared__ float sS[64], sT[64];
  __shared__ float sCAM[NJ*NJ];

  const int lane = threadIdx.x;
  const int g = lane >> 4;
  const int l15 = lane & 15;
  const int row_base = blockIdx.x * TILE_ROWS;

  /* zero alpha (swizzle-invariant), stage cam */
  {
    uint4 z4; z4.x=0; z4.y=0; z4.z=0; z4.w=0;
    uint4* az = (uint4*)sALPHA;
    #pragma unroll
    for (int i=0;i<8;++i) az[lane*8+i] = z4;
    for (int i=lane;i<NJ*NJ;i+=64) sCAM[i] = cam[i];
  }

  /* ---- 1: x A-fragments (bf16), kept in regs for both GEMMs ---- */
  short8 xf[4][4];
  #pragma unroll
  for (int mi=0; mi<4; ++mi){
    int r = 16*mi + l15;
    int grow = row_base + r;
    bool valid = (r < TILE_ROWS) && (grow < ROWS_TOTAL);
    const float* xrow = x + (size_t)grow*128;
    #pragma unroll
    for (int ks=0; ks<4; ++ks){
      int k0 = 32*ks + 8*g;
      float4 v0, v1;
      if (valid){ v0 = *(const float4*)(xrow + k0); v1 = *(const float4*)(xrow + k0 + 4); }
      else { v0 = make_float4(0.f,0.f,0.f,0.f); v1 = v0; }
      short8 f;
      f[0]=(short)f2bf(v0.x); f[1]=(short)f2bf(v0.y); f[2]=(short)f2bf(v0.z); f[3]=(short)f2bf(v0.w);
      f[4]=(short)f2bf(v1.x); f[5]=(short)f2bf(v1.y); f[6]=(short)f2bf(v1.z); f[7]=(short)f2bf(v1.w);
      xf[mi][ks] = f;
    }
  }

  /* ---- 2: h = x @ W1 ---- */
  f32x4 hacc[4][8];
  {
    f32x4 z; z[0]=0.f; z[1]=0.f; z[2]=0.f; z[3]=0.f;
    #pragma unroll
    for (int mi=0;mi<4;++mi)
      #pragma unroll
      for (int nt=0;nt<8;++nt) hacc[mi][nt]=z;
  }
  #pragma unroll
  for (int ks=0;ks<4;++ks){
    short8 bf[8];
    #pragma unroll
    for (int nt=0;nt<8;++nt)
      bf[nt] = *(const short8*)(w1p + (size_t)(((ks*8)+nt)*64 + lane)*8);
    #pragma unroll
    for (int mi=0;mi<4;++mi)
      #pragma unroll
      for (int nt=0;nt<8;++nt)
        hacc[mi][nt] = __builtin_amdgcn_mfma_f32_16x16x32_bf16(xf[mi][ks], bf[nt], hacc[mi][nt], 0,0,0);
  }

  /* ---- 3: s,t via w_s/w_t, reduce over lane groups ---- */
  {
    float sv[4]={0.f,0.f,0.f,0.f}, tv[4]={0.f,0.f,0.f,0.f};
    #pragma unroll
    for (int ks=0;ks<4;++ks){
      int k0 = 32*ks + 8*g;
      float4 w0 = *(const float4*)(wsv + k0); float4 w1v = *(const float4*)(wsv + k0 + 4);
      float4 t0 = *(const float4*)(wtv + k0); float4 t1 = *(const float4*)(wtv + k0 + 4);
      float wsa[8] = {w0.x,w0.y,w0.z,w0.w,w1v.x,w1v.y,w1v.z,w1v.w};
      float wta[8] = {t0.x,t0.y,t0.z,t0.w,t1.x,t1.y,t1.z,t1.w};
      #pragma unroll
      for (int mi=0;mi<4;++mi)
        #pragma unroll
        for (int e=0;e<8;++e){
          float xe = bf2f((uint16_t)xf[mi][ks][e]);
          sv[mi] += xe*wsa[e]; tv[mi] += xe*wta[e];
        }
    }
    #pragma unroll
    for (int mi=0;mi<4;++mi){
      float v=sv[mi]; v += __shfl_xor(v,16); v += __shfl_xor(v,32); sv[mi]=v;
      float t=tv[mi]; t += __shfl_xor(t,16); t += __shfl_xor(t,32); tv[mi]=t;
    }
    if (lane < 16){
      #pragma unroll
      for (int mi=0;mi<4;++mi){ sS[16*mi+lane]=sv[mi]; sT[16*mi+lane]=tv[mi]; }
    }
  }

  /* ---- 4: h -> LDS transposed h_T[c][r], XOR-swizzled, packed b64 ---- */
  #pragma unroll
  for (int mi=0;mi<4;++mi)
    #pragma unroll
    for (int nt=0;nt<8;++nt){
      int c = 16*nt + l15;
      int r0 = 16*mi + 4*g;
      uint32_t lo = (uint32_t)f2bf(hacc[mi][nt][0]) | ((uint32_t)f2bf(hacc[mi][nt][1])<<16);
      uint32_t hi = (uint32_t)f2bf(hacc[mi][nt][2]) | ((uint32_t)f2bf(hacc[mi][nt][3])<<16);
      int addr = (c*128 + r0*2) ^ ((c&7)<<4);
      uint2 w; w.x=lo; w.y=hi;
      *(uint2*)((char*)sHT + addr) = w;
    }
  __syncthreads();

  /* ---- 5: per-lane softmax row -> alpha (block-diagonal) ---- */
  {
    int r = lane;
    if (r < TILE_ROWS){
      int q = (r>=42)?2:((r>=21)?1:0);
      int i = r - 21*q, base = 21*q;
      float s_r = sS[r];
      float ev[NJ]; float m = -1e30f;
      #pragma unroll
      for (int j=0;j<NJ;++j){
        float e = s_r + sT[base+j];
        e = e>0.f ? e : 0.2f*e;
        ev[j]=e; m = fmaxf(m,e);
      }
      float sum=0.f;
      #pragma unroll
      for (int j=0;j<NJ;++j){ float p = __expf(ev[j]-m); ev[j]=p; sum+=p; }
      float inv = 1.f/sum;
      #pragma unroll
      for (int j=0;j<NJ;++j){
        uint16_t ab = f2bf(sCAM[i*NJ+j]*ev[j]*inv);
        int addr = (r*128 + (base+j)*2) ^ ((r&7)<<4);
        *(uint16_t*)((char*)sALPHA + addr) = ab;
      }
    }
  }
  __syncthreads();

  /* ---- 6: x_agg^T = h^T @ alpha^T  (M=128 feat, K=64 rows, N=64 rows) ---- */
  f32x4 agg[8][4];
  {
    f32x4 z; z[0]=0.f; z[1]=0.f; z[2]=0.f; z[3]=0.f;
    #pragma unroll
    for (int mt=0;mt<8;++mt)
      #pragma unroll
      for (int nt2=0;nt2<4;++nt2) agg[mt][nt2]=z;
  }
  #pragma unroll
  for (int ks2=0;ks2<2;++ks2){
    int kb = 32*ks2 + 8*g;
    short8 bfrag[4];
    #pragma unroll
    for (int nt2=0;nt2<4;++nt2){
      int n = 16*nt2 + l15;
      int addr = (n*128 + kb*2) ^ ((n&7)<<4);
      bfrag[nt2] = *(const short8*)((char*)sALPHA + addr);
    }
    #pragma unroll
    for (int mt=0;mt<8;++mt){
      int mm = 16*mt + l15;
      int addr = (mm*128 + kb*2) ^ ((mm&7)<<4);
      short8 afrag = *(const short8*)((char*)sHT + addr);
      #pragma unroll
      for (int nt2=0;nt2<4;++nt2)
        agg[mt][nt2] = __builtin_amdgcn_mfma_f32_16x16x32_bf16(afrag, bfrag[nt2], agg[mt][nt2], 0,0,0);
    }
  }
  __syncthreads();   /* h_T reads done before overwrite */

  /* ---- 7: x_agg^T (C-layout) -> LDS X_AGG[64][128] row-major, packed b64 ---- */
  #pragma unroll
  for (int mt=0;mt<8;++mt)
    #pragma unroll
    for (int nt2=0;nt2<4;++nt2){
      int f0 = 16*mt + 4*g;
      int samp = 16*nt2 + l15;
      uint32_t lo = (uint32_t)f2bf(agg[mt][nt2][0]) | ((uint32_t)f2bf(agg[mt][nt2][1])<<16);
      uint32_t hi = (uint32_t)f2bf(agg[mt][nt2][2]) | ((uint32_t)f2bf(agg[mt][nt2][3])<<16);
      int addr = (samp*256 + f0*2) ^ ((samp&7)<<4);
      uint2 w; w.x=lo; w.y=hi;
      *(uint2*)((char*)sHT + addr) = w;
    }
  __syncthreads();

  /* ---- 8: out = x_agg@W2a + x3@W2b + bias ---- */
  f32x4 oacc[4][8];
  #pragma unroll
  for (int nt=0;nt<8;++nt){
    float b = bias[16*nt + l15];
    #pragma unroll
    for (int mi=0;mi<4;++mi){ f32x4 v; v[0]=b; v[1]=b; v[2]=b; v[3]=b; oacc[mi][nt]=v; }
  }
  #pragma unroll
  for (int ks=0;ks<4;++ks){
    short8 af[4];
    #pragma unroll
    for (int mi=0;mi<4;++mi){
      int mm = 16*mi + l15;
      int addr = (mm*256 + (32*ks + 8*g)*2) ^ ((mm&7)<<4);
      af[mi] = *(const short8*)((char*)sHT + addr);
    }
    #pragma unroll
    for (int nt=0;nt<8;++nt){
      short8 bfa = *(const short8*)(w2ap + (size_t)(((ks*8)+nt)*64 + lane)*8);
      #pragma unroll
      for (int mi=0;mi<4;++mi)
        oacc[mi][nt] = __builtin_amdgcn_mfma_f32_16x16x32_bf16(af[mi], bfa, oacc[mi][nt], 0,0,0);
    }
    #pragma unroll
    for (int nt=0;nt<8;++nt){
      short8 bfb = *(const short8*)(w2bp + (size_t)(((ks*8)+nt)*64 + lane)*8);
      #pragma unroll
      for (int mi=0;mi<4;++mi)
        oacc[mi][nt] = __builtin_amdgcn_mfma_f32_16x16x32_bf16(xf[mi][ks], bfb, oacc[mi][nt], 0,0,0);
    }
  }

  /* ---- 9: ELU + predicated store ---- */
  #pragma unroll
  for (int mi=0;mi<4;++mi){
    #pragma unroll
    for (int q=0;q<4;++q){
      int r = 16*mi + 4*g + q;
      int grow = row_base + r;
      if (r < TILE_ROWS && grow < ROWS_TOTAL){
        float* orow = out + (size_t)grow*128;
        #pragma unroll
        for (int nt=0;nt<8;++nt){
          float v = oacc[mi][nt][q];
          v = v > 0.f ? v : (__expf(v) - 1.f);
          orow[16*nt + l15] = v;
        }
      }
    }
  }
}

extern "C" void kernel_launch(void* const* d_in, const int* in_sizes, int n_in,
                              void* d_out, int out_size, void* d_ws, size_t ws_size,
                              hipStream_t stream) {
  const float* x   = (const float*)d_in[0];
  const float* cam = (const float*)d_in[1];
  const float* W1  = (const float*)d_in[2];
  const float* a   = (const float*)d_in[3];
  const float* W2w = (const float*)d_in[4];
  const float* W2b = (const float*)d_in[5];
  float* out = (float*)d_out;

  char* ws = (char*)d_ws;
  uint16_t* w1p  = (uint16_t*)(ws + 0);
  uint16_t* w2ap = (uint16_t*)(ws + 32768);
  uint16_t* w2bp = (uint16_t*)(ws + 65536);
  float*    wsv  = (float*)(ws + 98304);
  float*    wtv  = (float*)(ws + 98816);

  pack_kernel<<<192, 256, 0, stream>>>(W1, W2w, w1p, w2ap, w2bp);
  wst_kernel<<<1, 128, 0, stream>>>(W1, a, wsv, wtv);
  camgat_kernel<<<NTILES, 64, 0, stream>>>(x, cam, W2b, w1p, w2ap, w2bp, wsv, wtv, out);
}

// Round 3
// 137.530 us; speedup vs baseline: 1.2819x; 1.2819x over previous
//
#include <hip/hip_runtime.h>
#include <hip/hip_bf16.h>
#include <stdint.h>

#define NJ 21
#define ROWS_TOTAL (16384*21)      /* 344064 */
#define TILE_ROWS 63               /* 3 batches per wave */
#define NTILES ((ROWS_TOTAL + TILE_ROWS - 1)/TILE_ROWS)  /* 5462 */

typedef __attribute__((ext_vector_type(8))) short short8;
typedef __attribute__((ext_vector_type(4))) float f32x4;

__device__ __forceinline__ uint16_t f2bf(float f){
  union{float f; uint32_t u;} v; v.f = f;
  uint32_t r = v.u + 0x7FFF + ((v.u>>16)&1);
  return (uint16_t)(r>>16);
}

/* which=0: Up[frag] = bf16( (W1@W2a)[k][n] )   (U = W1 @ W2_w[0:128])
   which=1: w2bp[frag] = bf16( W2_w[128+k][n] )
   frag layout: buf[(((ks*8)+nt)*64 + lane)*8 + e] = M[k=32ks+8*(lane>>4)+e][n=16nt+(lane&15)] */
__global__ void pack_kernel(const float* __restrict__ W1, const float* __restrict__ W2,
                            uint16_t* __restrict__ Up, uint16_t* __restrict__ w2bp){
  int idx = blockIdx.x*256 + threadIdx.x;       /* 0..32767 */
  int which = idx >> 14;
  int sub = idx & 16383;
  int e = sub & 7, lane = (sub>>3)&63, nt = (sub>>9)&7, ks = sub>>12;
  int k = 32*ks + 8*(lane>>4) + e;
  int n = 16*nt + (lane&15);
  if (which==0){
    float acc = 0.f;
    for (int p=0;p<128;++p) acc += W1[k*128+p]*W2[p*128+n];
    Up[sub] = f2bf(acc);
  } else {
    w2bp[sub] = f2bf(W2[(128+k)*128+n]);
  }
}

/* w_s = W1 @ a1, w_t = W1 @ a2 (associativity: s = x @ (W1@a1)) */
__global__ void wst_kernel(const float* __restrict__ W1, const float* __restrict__ a,
                           float* __restrict__ wsv, float* __restrict__ wtv){
  int f = threadIdx.x;  /* 128 threads */
  float s=0.f, t=0.f;
  for (int p=0; p<128; ++p){ float w = W1[f*128+p]; s += w*a[p]; t += w*a[128+p]; }
  wsv[f]=s; wtv[f]=t;
}

__global__ __launch_bounds__(64) void camgat_kernel(
    const float* __restrict__ x, const float* __restrict__ cam,
    const float* __restrict__ bias,
    const uint16_t* __restrict__ Up, const uint16_t* __restrict__ w2bp,
    const float* __restrict__ wsv, const float* __restrict__ wtv,
    float* __restrict__ out)
{
  __shared__ uint16_t sALPHA[64*64];   /* block-diag alpha, row-major, swizzled */
  __shared__ uint16_t sUT[64*64];      /* u^T half: [feat_local 64][sample 64], swizzled */
  __shared__ float sS[64], sT[64];

  const int lane = threadIdx.x;
  const int g = lane >> 4;
  const int l15 = lane & 15;
  const int row_base = blockIdx.x * TILE_ROWS;

  /* zero alpha (swizzle-invariant: zeros everywhere) */
  {
    uint4 z4; z4.x=0; z4.y=0; z4.z=0; z4.w=0;
    uint4* az = (uint4*)sALPHA;
    #pragma unroll
    for (int i=0;i<8;++i) az[i*64+lane] = z4;
  }

  /* ---- 1: load x as bf16 A-frags; accumulate s,t from f32 values ---- */
  short8 xf[4][4];
  float sv[4]={0.f,0.f,0.f,0.f}, tv[4]={0.f,0.f,0.f,0.f};
  #pragma unroll
  for (int ks=0; ks<4; ++ks){
    int k0 = 32*ks + 8*g;
    float4 w0 = *(const float4*)(wsv + k0); float4 w1v = *(const float4*)(wsv + k0 + 4);
    float4 t0 = *(const float4*)(wtv + k0); float4 t1 = *(const float4*)(wtv + k0 + 4);
    #pragma unroll
    for (int mi=0; mi<4; ++mi){
      int r = 16*mi + l15;
      int grow = row_base + r;
      bool valid = (r < TILE_ROWS) && (grow < ROWS_TOTAL);
      const float* xrow = x + (size_t)grow*128;
      float4 v0, v1;
      if (valid){ v0 = *(const float4*)(xrow + k0); v1 = *(const float4*)(xrow + k0 + 4); }
      else { v0 = make_float4(0.f,0.f,0.f,0.f); v1 = v0; }
      short8 f;
      f[0]=(short)f2bf(v0.x); f[1]=(short)f2bf(v0.y); f[2]=(short)f2bf(v0.z); f[3]=(short)f2bf(v0.w);
      f[4]=(short)f2bf(v1.x); f[5]=(short)f2bf(v1.y); f[6]=(short)f2bf(v1.z); f[7]=(short)f2bf(v1.w);
      xf[mi][ks] = f;
      sv[mi] += v0.x*w0.x + v0.y*w0.y + v0.z*w0.z + v0.w*w0.w
              + v1.x*w1v.x + v1.y*w1v.y + v1.z*w1v.z + v1.w*w1v.w;
      tv[mi] += v0.x*t0.x + v0.y*t0.y + v0.z*t0.z + v0.w*t0.w
              + v1.x*t1.x + v1.y*t1.y + v1.z*t1.z + v1.w*t1.w;
    }
  }
  /* reduce across g-groups (lanes 16 apart, same l15) */
  #pragma unroll
  for (int mi=0;mi<4;++mi){
    float v=sv[mi]; v += __shfl_xor(v,16); v += __shfl_xor(v,32); sv[mi]=v;
    float t=tv[mi]; t += __shfl_xor(t,16); t += __shfl_xor(t,32); tv[mi]=t;
  }
  if (lane < 16){
    #pragma unroll
    for (int mi=0;mi<4;++mi){ sS[16*mi+lane]=sv[mi]; sT[16*mi+lane]=tv[mi]; }
  }
  __syncthreads();

  /* ---- 2: per-lane softmax row -> alpha (block-diagonal, swizzled) ---- */
  if (lane < TILE_ROWS){
    int q = (lane>=42)?2:((lane>=21)?1:0);
    int i = lane - 21*q, base = 21*q;
    float s_r = sS[lane];
    float ev[NJ]; float m = -1e30f;
    #pragma unroll
    for (int j=0;j<NJ;++j){
      float e = s_r + sT[base+j];
      e = e>0.f ? e : 0.2f*e;
      ev[j]=e; m = fmaxf(m,e);
    }
    float sum=0.f;
    #pragma unroll
    for (int j=0;j<NJ;++j){ float p = __expf(ev[j]-m); ev[j]=p; sum+=p; }
    float inv = 1.f/sum;
    #pragma unroll
    for (int j=0;j<NJ;++j){
      uint16_t ab = f2bf(cam[i*NJ+j]*ev[j]*inv);
      int addr = (lane*128 + (base+j)*2) ^ ((lane&7)<<4);
      *(uint16_t*)((char*)sALPHA + addr) = ab;
    }
  }

  /* ---- 3: two feature halves: u = x@U -> LDS u^T -> out = bias + x@W2b + alpha@u ---- */
  #pragma unroll
  for (int h=0; h<2; ++h){
    /* u-GEMM (64 out-feats) */
    f32x4 uacc[4][4];
    {
      f32x4 z; z[0]=0.f; z[1]=0.f; z[2]=0.f; z[3]=0.f;
      #pragma unroll
      for (int mi=0;mi<4;++mi)
        #pragma unroll
        for (int ntl=0;ntl<4;++ntl) uacc[mi][ntl]=z;
    }
    #pragma unroll
    for (int ks=0;ks<4;++ks){
      short8 bf[4];
      #pragma unroll
      for (int ntl=0;ntl<4;++ntl)
        bf[ntl] = *(const short8*)(Up + (size_t)(((ks*8)+(4*h+ntl))*64 + lane)*8);
      #pragma unroll
      for (int mi=0;mi<4;++mi)
        #pragma unroll
        for (int ntl=0;ntl<4;++ntl)
          uacc[mi][ntl] = __builtin_amdgcn_mfma_f32_16x16x32_bf16(xf[mi][ks], bf[ntl], uacc[mi][ntl], 0,0,0);
    }
    /* pack u^T -> LDS (swizzled); lane holds u[sample=16mi+4g+reg][feat=16ntl+l15] */
    #pragma unroll
    for (int mi=0;mi<4;++mi)
      #pragma unroll
      for (int ntl=0;ntl<4;++ntl){
        int c = 16*ntl + l15;        /* feat_local */
        int r0 = 16*mi + 4*g;        /* sample */
        uint32_t lo = (uint32_t)f2bf(uacc[mi][ntl][0]) | ((uint32_t)f2bf(uacc[mi][ntl][1])<<16);
        uint32_t hi = (uint32_t)f2bf(uacc[mi][ntl][2]) | ((uint32_t)f2bf(uacc[mi][ntl][3])<<16);
        int addr = (c*128 + r0*2) ^ ((c&7)<<4);
        uint2 w; w.x=lo; w.y=hi;
        *(uint2*)((char*)sUT + addr) = w;
      }
    __syncthreads();   /* uT (and alpha on h=0) visible */

    /* oacc = bias + x@W2b + alpha@u */
    f32x4 oacc[4][4];
    #pragma unroll
    for (int ntl=0;ntl<4;++ntl){
      float b = bias[16*(4*h+ntl) + l15];
      #pragma unroll
      for (int mi=0;mi<4;++mi){ f32x4 v; v[0]=b; v[1]=b; v[2]=b; v[3]=b; oacc[mi][ntl]=v; }
    }
    #pragma unroll
    for (int ks=0;ks<4;++ks){
      short8 bf[4];
      #pragma unroll
      for (int ntl=0;ntl<4;++ntl)
        bf[ntl] = *(const short8*)(w2bp + (size_t)(((ks*8)+(4*h+ntl))*64 + lane)*8);
      #pragma unroll
      for (int mi=0;mi<4;++mi)
        #pragma unroll
        for (int ntl=0;ntl<4;++ntl)
          oacc[mi][ntl] = __builtin_amdgcn_mfma_f32_16x16x32_bf16(xf[mi][ks], bf[ntl], oacc[mi][ntl], 0,0,0);
    }
    #pragma unroll
    for (int ks2=0;ks2<2;++ks2){
      int kb = (32*ks2 + 8*g)*2;
      short8 afr[4], bfr[4];
      #pragma unroll
      for (int mi=0;mi<4;++mi){
        int i = 16*mi + l15;
        int addr = (i*128 + kb) ^ ((i&7)<<4);
        afr[mi] = *(const short8*)((char*)sALPHA + addr);
      }
      #pragma unroll
      for (int ntl=0;ntl<4;++ntl){
        int n = 16*ntl + l15;
        int addr = (n*128 + kb) ^ ((n&7)<<4);
        bfr[ntl] = *(const short8*)((char*)sUT + addr);
      }
      #pragma unroll
      for (int mi=0;mi<4;++mi)
        #pragma unroll
        for (int ntl=0;ntl<4;++ntl)
          oacc[mi][ntl] = __builtin_amdgcn_mfma_f32_16x16x32_bf16(afr[mi], bfr[ntl], oacc[mi][ntl], 0,0,0);
    }

    /* ELU + predicated store of this feature half */
    #pragma unroll
    for (int mi=0;mi<4;++mi){
      #pragma unroll
      for (int q=0;q<4;++q){
        int r = 16*mi + 4*g + q;
        int grow = row_base + r;
        if (r < TILE_ROWS && grow < ROWS_TOTAL){
          float* orow = out + (size_t)grow*128 + 64*h;
          #pragma unroll
          for (int ntl=0;ntl<4;++ntl){
            float v = oacc[mi][ntl][q];
            v = v > 0.f ? v : (__expf(v) - 1.f);
            orow[16*ntl + l15] = v;
          }
        }
      }
    }
    __syncthreads();   /* protect sUT before next half overwrites */
  }
}

extern "C" void kernel_launch(void* const* d_in, const int* in_sizes, int n_in,
                              void* d_out, int out_size, void* d_ws, size_t ws_size,
                              hipStream_t stream) {
  const float* x   = (const float*)d_in[0];
  const float* cam = (const float*)d_in[1];
  const float* W1  = (const float*)d_in[2];
  const float* a   = (const float*)d_in[3];
  const float* W2w = (const float*)d_in[4];
  const float* W2b = (const float*)d_in[5];
  float* out = (float*)d_out;

  char* ws = (char*)d_ws;
  uint16_t* Up   = (uint16_t*)(ws + 0);
  uint16_t* w2bp = (uint16_t*)(ws + 32768);
  float*    wsv  = (float*)(ws + 65536);
  float*    wtv  = (float*)(ws + 66048);

  pack_kernel<<<128, 256, 0, stream>>>(W1, W2w, Up, w2bp);
  wst_kernel<<<1, 128, 0, stream>>>(W1, a, wsv, wtv);
  camgat_kernel<<<NTILES, 64, 0, stream>>>(x, cam, W2b, Up, w2bp, wsv, wtv, out);
}

// Round 4
// 136.138 us; speedup vs baseline: 1.2950x; 1.0102x over previous
//
#include <hip/hip_runtime.h>
#include <hip/hip_bf16.h>
#include <stdint.h>

#define NJ 21
#define ROWS_TOTAL (16384*21)      /* 344064 */
#define TILE_ROWS 63               /* 3 batches per wave */
#define NTILES ((ROWS_TOTAL + TILE_ROWS - 1)/TILE_ROWS)  /* 5462 */
#define WPG 4                      /* waves (tiles) per workgroup */
#define NWG ((NTILES + WPG - 1)/WPG)

typedef __attribute__((ext_vector_type(8))) short short8;
typedef __attribute__((ext_vector_type(4))) float f32x4;

/* wave-local LDS fence: cross-lane visibility within one wave (no WG barrier) */
#define WAVE_SYNC() asm volatile("s_waitcnt lgkmcnt(0)" ::: "memory")

__device__ __forceinline__ uint16_t f2bf(float f){
  union{float f; uint32_t u;} v; v.f = f;
  uint32_t r = v.u + 0x7FFF + ((v.u>>16)&1);
  return (uint16_t)(r>>16);
}

/* which=0: Up[frag] = bf16( (W1@W2a)[k][n] )   (U = W1 @ W2_w[0:128])
   which=1: w2bp[frag] = bf16( W2_w[128+k][n] )
   frag layout: buf[(((ks*8)+nt)*64 + lane)*8 + e] = M[k=32ks+8*(lane>>4)+e][n=16nt+(lane&15)] */
__global__ void pack_kernel(const float* __restrict__ W1, const float* __restrict__ W2,
                            uint16_t* __restrict__ Up, uint16_t* __restrict__ w2bp){
  int idx = blockIdx.x*256 + threadIdx.x;       /* 0..32767 */
  int which = idx >> 14;
  int sub = idx & 16383;
  int e = sub & 7, lane = (sub>>3)&63, nt = (sub>>9)&7, ks = sub>>12;
  int k = 32*ks + 8*(lane>>4) + e;
  int n = 16*nt + (lane&15);
  if (which==0){
    float acc = 0.f;
    for (int p=0;p<128;++p) acc += W1[k*128+p]*W2[p*128+n];
    Up[sub] = f2bf(acc);
  } else {
    w2bp[sub] = f2bf(W2[(128+k)*128+n]);
  }
}

/* w_s = W1 @ a1, w_t = W1 @ a2 (associativity: s = x @ (W1@a1)) */
__global__ void wst_kernel(const float* __restrict__ W1, const float* __restrict__ a,
                           float* __restrict__ wsv, float* __restrict__ wtv){
  int f = threadIdx.x;  /* 128 threads */
  float s=0.f, t=0.f;
  for (int p=0; p<128; ++p){ float w = W1[f*128+p]; s += w*a[p]; t += w*a[128+p]; }
  wsv[f]=s; wtv[f]=t;
}

__global__ __launch_bounds__(256) void camgat_kernel(
    const float* __restrict__ x, const float* __restrict__ cam,
    const float* __restrict__ bias,
    const uint16_t* __restrict__ Up, const uint16_t* __restrict__ w2bp,
    const float* __restrict__ wsv, const float* __restrict__ wtv,
    float* __restrict__ out)
{
  __shared__ uint16_t sALPHA[WPG][64*64];   /* per-wave: block-diag alpha, swizzled */
  __shared__ uint16_t sUT[WPG][64*64];      /* per-wave: u^T half [feat64][sample64], swizzled */
  __shared__ float sS[WPG][64], sT[WPG][64];

  const int tid  = threadIdx.x;
  const int wv   = tid >> 6;
  const int lane = tid & 63;
  const int g = lane >> 4;
  const int l15 = lane & 15;
  const int row_base = (blockIdx.x*WPG + wv) * TILE_ROWS;

  uint16_t* myALPHA = sALPHA[wv];
  uint16_t* myUT    = sUT[wv];
  float*    mySS    = sS[wv];
  float*    myST    = sT[wv];

  /* zero alpha (swizzle-invariant: zeros everywhere) */
  {
    uint4 z4; z4.x=0; z4.y=0; z4.z=0; z4.w=0;
    uint4* az = (uint4*)myALPHA;
    #pragma unroll
    for (int i=0;i<8;++i) az[i*64+lane] = z4;
  }

  /* ---- 1: load x as bf16 A-frags; accumulate s,t from f32 values ---- */
  short8 xf[4][4];
  float sv[4]={0.f,0.f,0.f,0.f}, tv[4]={0.f,0.f,0.f,0.f};
  #pragma unroll
  for (int ks=0; ks<4; ++ks){
    int k0 = 32*ks + 8*g;
    float4 w0 = *(const float4*)(wsv + k0); float4 w1v = *(const float4*)(wsv + k0 + 4);
    float4 t0 = *(const float4*)(wtv + k0); float4 t1 = *(const float4*)(wtv + k0 + 4);
    #pragma unroll
    for (int mi=0; mi<4; ++mi){
      int r = 16*mi + l15;
      int grow = row_base + r;
      bool valid = (r < TILE_ROWS) && (grow < ROWS_TOTAL);
      const float* xrow = x + (size_t)grow*128;
      float4 v0, v1;
      if (valid){ v0 = *(const float4*)(xrow + k0); v1 = *(const float4*)(xrow + k0 + 4); }
      else { v0 = make_float4(0.f,0.f,0.f,0.f); v1 = v0; }
      short8 f;
      f[0]=(short)f2bf(v0.x); f[1]=(short)f2bf(v0.y); f[2]=(short)f2bf(v0.z); f[3]=(short)f2bf(v0.w);
      f[4]=(short)f2bf(v1.x); f[5]=(short)f2bf(v1.y); f[6]=(short)f2bf(v1.z); f[7]=(short)f2bf(v1.w);
      xf[mi][ks] = f;
      sv[mi] += v0.x*w0.x + v0.y*w0.y + v0.z*w0.z + v0.w*w0.w
              + v1.x*w1v.x + v1.y*w1v.y + v1.z*w1v.z + v1.w*w1v.w;
      tv[mi] += v0.x*t0.x + v0.y*t0.y + v0.z*t0.z + v0.w*t0.w
              + v1.x*t1.x + v1.y*t1.y + v1.z*t1.z + v1.w*t1.w;
    }
  }
  /* reduce across g-groups (lanes 16 apart, same l15) */
  #pragma unroll
  for (int mi=0;mi<4;++mi){
    float v=sv[mi]; v += __shfl_xor(v,16); v += __shfl_xor(v,32); sv[mi]=v;
    float t=tv[mi]; t += __shfl_xor(t,16); t += __shfl_xor(t,32); tv[mi]=t;
  }
  if (lane < 16){
    #pragma unroll
    for (int mi=0;mi<4;++mi){ mySS[16*mi+lane]=sv[mi]; myST[16*mi+lane]=tv[mi]; }
  }
  WAVE_SYNC();   /* sS/sT + alpha zeros visible wave-wide */

  /* ---- 2: per-lane softmax row -> alpha (block-diagonal, swizzled) ---- */
  if (lane < TILE_ROWS){
    int q = (lane>=42)?2:((lane>=21)?1:0);
    int i = lane - 21*q, base = 21*q;
    float s_r = mySS[lane];
    float ev[NJ]; float m = -1e30f;
    #pragma unroll
    for (int j=0;j<NJ;++j){
      float e = s_r + myST[base+j];
      e = e>0.f ? e : 0.2f*e;
      ev[j]=e; m = fmaxf(m,e);
    }
    float sum=0.f;
    #pragma unroll
    for (int j=0;j<NJ;++j){ float p = __expf(ev[j]-m); ev[j]=p; sum+=p; }
    float inv = 1.f/sum;
    #pragma unroll
    for (int j=0;j<NJ;++j){
      uint16_t ab = f2bf(cam[i*NJ+j]*ev[j]*inv);
      int addr = (lane*128 + (base+j)*2) ^ ((lane&7)<<4);
      *(uint16_t*)((char*)myALPHA + addr) = ab;
    }
  }

  /* ---- 3: two feature halves: u = x@U -> LDS u^T -> out = bias + x@W2b + alpha@u ---- */
  #pragma unroll
  for (int h=0; h<2; ++h){
    /* u-GEMM (64 out-feats) */
    f32x4 uacc[4][4];
    {
      f32x4 z; z[0]=0.f; z[1]=0.f; z[2]=0.f; z[3]=0.f;
      #pragma unroll
      for (int mi=0;mi<4;++mi)
        #pragma unroll
        for (int ntl=0;ntl<4;++ntl) uacc[mi][ntl]=z;
    }
    #pragma unroll
    for (int ks=0;ks<4;++ks){
      short8 bf[4];
      #pragma unroll
      for (int ntl=0;ntl<4;++ntl)
        bf[ntl] = *(const short8*)(Up + (size_t)(((ks*8)+(4*h+ntl))*64 + lane)*8);
      #pragma unroll
      for (int mi=0;mi<4;++mi)
        #pragma unroll
        for (int ntl=0;ntl<4;++ntl)
          uacc[mi][ntl] = __builtin_amdgcn_mfma_f32_16x16x32_bf16(xf[mi][ks], bf[ntl], uacc[mi][ntl], 0,0,0);
    }
    /* pack u^T -> LDS (swizzled); lane holds u[sample=16mi+4g+reg][feat=16ntl+l15] */
    #pragma unroll
    for (int mi=0;mi<4;++mi)
      #pragma unroll
      for (int ntl=0;ntl<4;++ntl){
        int c = 16*ntl + l15;        /* feat_local */
        int r0 = 16*mi + 4*g;        /* sample */
        uint32_t lo = (uint32_t)f2bf(uacc[mi][ntl][0]) | ((uint32_t)f2bf(uacc[mi][ntl][1])<<16);
        uint32_t hi = (uint32_t)f2bf(uacc[mi][ntl][2]) | ((uint32_t)f2bf(uacc[mi][ntl][3])<<16);
        int addr = (c*128 + r0*2) ^ ((c&7)<<4);
        uint2 w; w.x=lo; w.y=hi;
        *(uint2*)((char*)myUT + addr) = w;
      }
    WAVE_SYNC();   /* uT (and alpha on h=0) visible wave-wide */

    /* oacc = bias + x@W2b + alpha@u */
    f32x4 oacc[4][4];
    #pragma unroll
    for (int ntl=0;ntl<4;++ntl){
      float b = bias[16*(4*h+ntl) + l15];
      #pragma unroll
      for (int mi=0;mi<4;++mi){ f32x4 v; v[0]=b; v[1]=b; v[2]=b; v[3]=b; oacc[mi][ntl]=v; }
    }
    #pragma unroll
    for (int ks=0;ks<4;++ks){
      short8 bf[4];
      #pragma unroll
      for (int ntl=0;ntl<4;++ntl)
        bf[ntl] = *(const short8*)(w2bp + (size_t)(((ks*8)+(4*h+ntl))*64 + lane)*8);
      #pragma unroll
      for (int mi=0;mi<4;++mi)
        #pragma unroll
        for (int ntl=0;ntl<4;++ntl)
          oacc[mi][ntl] = __builtin_amdgcn_mfma_f32_16x16x32_bf16(xf[mi][ks], bf[ntl], oacc[mi][ntl], 0,0,0);
    }
    #pragma unroll
    for (int ks2=0;ks2<2;++ks2){
      int kb = (32*ks2 + 8*g)*2;
      short8 afr[4], bfr[4];
      #pragma unroll
      for (int mi=0;mi<4;++mi){
        int i = 16*mi + l15;
        int addr = (i*128 + kb) ^ ((i&7)<<4);
        afr[mi] = *(const short8*)((char*)myALPHA + addr);
      }
      #pragma unroll
      for (int ntl=0;ntl<4;++ntl){
        int n = 16*ntl + l15;
        int addr = (n*128 + kb) ^ ((n&7)<<4);
        bfr[ntl] = *(const short8*)((char*)myUT + addr);
      }
      #pragma unroll
      for (int mi=0;mi<4;++mi)
        #pragma unroll
        for (int ntl=0;ntl<4;++ntl)
          oacc[mi][ntl] = __builtin_amdgcn_mfma_f32_16x16x32_bf16(afr[mi], bfr[ntl], oacc[mi][ntl], 0,0,0);
    }

    /* ELU + predicated store of this feature half */
    #pragma unroll
    for (int mi=0;mi<4;++mi){
      #pragma unroll
      for (int q=0;q<4;++q){
        int r = 16*mi + 4*g + q;
        int grow = row_base + r;
        if (r < TILE_ROWS && grow < ROWS_TOTAL){
          float* orow = out + (size_t)grow*128 + 64*h;
          #pragma unroll
          for (int ntl=0;ntl<4;++ntl){
            float v = oacc[mi][ntl][q];
            v = v > 0.f ? v : (__expf(v) - 1.f);
            orow[16*ntl + l15] = v;
          }
        }
      }
    }
    WAVE_SYNC();   /* drain myUT reads before next half overwrites */
  }
}

extern "C" void kernel_launch(void* const* d_in, const int* in_sizes, int n_in,
                              void* d_out, int out_size, void* d_ws, size_t ws_size,
                              hipStream_t stream) {
  const float* x   = (const float*)d_in[0];
  const float* cam = (const float*)d_in[1];
  const float* W1  = (const float*)d_in[2];
  const float* a   = (const float*)d_in[3];
  const float* W2w = (const float*)d_in[4];
  const float* W2b = (const float*)d_in[5];
  float* out = (float*)d_out;

  char* ws = (char*)d_ws;
  uint16_t* Up   = (uint16_t*)(ws + 0);
  uint16_t* w2bp = (uint16_t*)(ws + 32768);
  float*    wsv  = (float*)(ws + 65536);
  float*    wtv  = (float*)(ws + 66048);

  pack_kernel<<<128, 256, 0, stream>>>(W1, W2w, Up, w2bp);
  wst_kernel<<<1, 128, 0, stream>>>(W1, a, wsv, wtv);
  camgat_kernel<<<NWG, 64*WPG, 0, stream>>>(x, cam, W2b, Up, w2bp, wsv, wtv, out);
}

// Round 5
// 111.814 us; speedup vs baseline: 1.5767x; 1.2175x over previous
//
#include <hip/hip_runtime.h>
#include <hip/hip_bf16.h>
#include <stdint.h>

#define NJ 21
#define ROWS_TOTAL (16384*21)      /* 344064 */
#define TILE_ROWS 63               /* 3 batches per wave */
#define NTILES ((ROWS_TOTAL + TILE_ROWS - 1)/TILE_ROWS)  /* 5462 */
#define WPG 4                      /* waves (tiles) per workgroup */
#define NWG ((NTILES + WPG - 1)/WPG)

typedef __attribute__((ext_vector_type(8))) short short8;
typedef __attribute__((ext_vector_type(4))) float f32x4;

/* wave-local LDS fence: cross-lane visibility within one wave (no WG barrier) */
#define WAVE_SYNC() asm volatile("s_waitcnt lgkmcnt(0)" ::: "memory")

__device__ __forceinline__ uint16_t f2bf(float f){
  union{float f; uint32_t u;} v; v.f = f;
  uint32_t r = v.u + 0x7FFF + ((v.u>>16)&1);
  return (uint16_t)(r>>16);
}

/* idx<16384:  Up[frag]   = bf16( (W1@W2a)[k][n] )      (U = W1 @ W2_w[0:128])
   idx<32768:  w2bp[frag] = bf16( W2_w[128+k][n] )
   idx<34816:  stp[frag]  = B-tile [ws | wt | 0...]:  n==0 -> (W1@a1)[k], n==1 -> (W1@a2)[k]
   frag layout: buf[(tile*64 + lane)*8 + e] = M[k=32ks+8*(lane>>4)+e][n=16nt+(lane&15)] */
__global__ void pack_kernel(const float* __restrict__ W1, const float* __restrict__ W2,
                            const float* __restrict__ a,
                            uint16_t* __restrict__ Up, uint16_t* __restrict__ w2bp,
                            uint16_t* __restrict__ stp){
  int idx = blockIdx.x*256 + threadIdx.x;       /* 0..34815 */
  if (idx < 32768){
    int which = idx >> 14;
    int sub = idx & 16383;
    int e = sub & 7, lane = (sub>>3)&63, nt = (sub>>9)&7, ks = sub>>12;
    int k = 32*ks + 8*(lane>>4) + e;
    int n = 16*nt + (lane&15);
    if (which==0){
      float acc = 0.f;
      for (int p=0;p<128;++p) acc += W1[k*128+p]*W2[p*128+n];
      Up[sub] = f2bf(acc);
    } else {
      w2bp[sub] = f2bf(W2[(128+k)*128+n]);
    }
  } else if (idx < 34816){
    int sub = idx - 32768;        /* 0..2047 */
    int e = sub & 7, lane = (sub>>3)&63, ks = (sub>>9)&3;
    int k = 32*ks + 8*(lane>>4) + e;
    int l15 = lane & 15;
    float v = 0.f;
    if (l15 == 0){ for (int p=0;p<128;++p) v += W1[k*128+p]*a[p]; }
    else if (l15 == 1){ for (int p=0;p<128;++p) v += W1[k*128+p]*a[128+p]; }
    stp[sub] = f2bf(v);
  }
}

__global__ __launch_bounds__(256,2) void camgat_kernel(
    const float* __restrict__ x, const float* __restrict__ cam,
    const float* __restrict__ bias,
    const uint16_t* __restrict__ Up, const uint16_t* __restrict__ w2bp,
    const uint16_t* __restrict__ stp,
    float* __restrict__ out)
{
  __shared__ uint16_t sALPHA[WPG][64*64];   /* per-wave: block-diag alpha, swizzled */
  __shared__ uint16_t sUT[WPG][64*64];      /* per-wave: u^T half [feat64][sample64], swizzled */
  __shared__ float sS[WPG][64], sT[WPG][64];

  const int tid  = threadIdx.x;
  const int wv   = tid >> 6;
  const int lane = tid & 63;
  const int g = lane >> 4;
  const int l15 = lane & 15;
  const long row_base = (long)(blockIdx.x*WPG + wv) * TILE_ROWS;

  uint16_t* myALPHA = sALPHA[wv];
  uint16_t* myUT    = sUT[wv];
  float*    mySS    = sS[wv];
  float*    myST    = sT[wv];

  /* zero alpha (swizzle-invariant: zeros everywhere) */
  {
    uint4 z4; z4.x=0; z4.y=0; z4.z=0; z4.w=0;
    uint4* az = (uint4*)myALPHA;
    #pragma unroll
    for (int i=0;i<8;++i) az[i*64+lane] = z4;
  }

  /* ---- 1: BURST all 32 x float4 loads (clamped rows, unconditional), then convert ---- */
  float4 xraw[4][8];
  #pragma unroll
  for (int mi=0; mi<4; ++mi){
    long grow = row_base + 16*mi + l15;
    if (grow > (long)ROWS_TOTAL-1) grow = (long)ROWS_TOTAL-1;
    const float* xrow = x + grow*128;
    #pragma unroll
    for (int ks=0; ks<4; ++ks){
      xraw[mi][2*ks]   = *(const float4*)(xrow + 32*ks + 8*g);
      xraw[mi][2*ks+1] = *(const float4*)(xrow + 32*ks + 8*g + 4);
    }
  }
  short8 xf[4][4];
  #pragma unroll
  for (int mi=0; mi<4; ++mi)
    #pragma unroll
    for (int ks=0; ks<4; ++ks){
      float4 v0 = xraw[mi][2*ks], v1 = xraw[mi][2*ks+1];
      short8 f;
      f[0]=(short)f2bf(v0.x); f[1]=(short)f2bf(v0.y); f[2]=(short)f2bf(v0.z); f[3]=(short)f2bf(v0.w);
      f[4]=(short)f2bf(v1.x); f[5]=(short)f2bf(v1.y); f[6]=(short)f2bf(v1.z); f[7]=(short)f2bf(v1.w);
      xf[mi][ks] = f;
    }

  /* ---- 2: two feature halves ---- */
  #pragma unroll
  for (int h=0; h<2; ++h){
    /* burst all weight frags for u-GEMM (plus st tile on h==0) */
    short8 bfu[4][4];
    #pragma unroll
    for (int ks=0;ks<4;++ks)
      #pragma unroll
      for (int ntl=0;ntl<4;++ntl)
        bfu[ks][ntl] = *(const short8*)(Up + (size_t)(((ks*8)+(4*h+ntl))*64 + lane)*8);
    short8 stf[4];
    if (h==0){
      #pragma unroll
      for (int ks=0;ks<4;++ks)
        stf[ks] = *(const short8*)(stp + (size_t)(ks*64 + lane)*8);
    }

    /* u-GEMM (64 out-feats) + st tile */
    f32x4 uacc[4][4]; f32x4 stacc[4];
    {
      f32x4 z; z[0]=0.f; z[1]=0.f; z[2]=0.f; z[3]=0.f;
      #pragma unroll
      for (int mi=0;mi<4;++mi){
        stacc[mi]=z;
        #pragma unroll
        for (int ntl=0;ntl<4;++ntl) uacc[mi][ntl]=z;
      }
    }
    #pragma unroll
    for (int ks=0;ks<4;++ks)
      #pragma unroll
      for (int mi=0;mi<4;++mi){
        #pragma unroll
        for (int ntl=0;ntl<4;++ntl)
          uacc[mi][ntl] = __builtin_amdgcn_mfma_f32_16x16x32_bf16(xf[mi][ks], bfu[ks][ntl], uacc[mi][ntl], 0,0,0);
        if (h==0)
          stacc[mi] = __builtin_amdgcn_mfma_f32_16x16x32_bf16(xf[mi][ks], stf[ks], stacc[mi], 0,0,0);
      }

    if (h==0){
      /* scatter s,t (C layout: col=l15, row=16mi+4g+q) */
      if (l15 == 0){
        #pragma unroll
        for (int mi=0;mi<4;++mi)
          #pragma unroll
          for (int q=0;q<4;++q) mySS[16*mi+4*g+q] = stacc[mi][q];
      } else if (l15 == 1){
        #pragma unroll
        for (int mi=0;mi<4;++mi)
          #pragma unroll
          for (int q=0;q<4;++q) myST[16*mi+4*g+q] = stacc[mi][q];
      }
      WAVE_SYNC();   /* s,t visible wave-wide (and alpha zeros drained) */

      /* per-lane softmax row -> alpha (block-diagonal, swizzled) */
      if (lane < TILE_ROWS){
        int qq = (lane>=42)?2:((lane>=21)?1:0);
        int i = lane - 21*qq, base = 21*qq;
        float s_r = mySS[lane];
        float ev[NJ]; float m = -1e30f;
        #pragma unroll
        for (int j=0;j<NJ;++j){
          float e = s_r + myST[base+j];
          e = e>0.f ? e : 0.2f*e;
          ev[j]=e; m = fmaxf(m,e);
        }
        float sum=0.f;
        #pragma unroll
        for (int j=0;j<NJ;++j){ float p = __expf(ev[j]-m); ev[j]=p; sum+=p; }
        float inv = 1.f/sum;
        #pragma unroll
        for (int j=0;j<NJ;++j){
          uint16_t ab = f2bf(cam[i*NJ+j]*ev[j]*inv);
          int addr = (lane*128 + (base+j)*2) ^ ((lane&7)<<4);
          *(uint16_t*)((char*)myALPHA + addr) = ab;
        }
      }
    }

    /* pack u^T -> LDS (swizzled); lane holds u[sample=16mi+4g+reg][feat=16ntl+l15] */
    #pragma unroll
    for (int mi=0;mi<4;++mi)
      #pragma unroll
      for (int ntl=0;ntl<4;++ntl){
        int c = 16*ntl + l15;        /* feat_local */
        int r0 = 16*mi + 4*g;        /* sample */
        uint32_t lo = (uint32_t)f2bf(uacc[mi][ntl][0]) | ((uint32_t)f2bf(uacc[mi][ntl][1])<<16);
        uint32_t hi = (uint32_t)f2bf(uacc[mi][ntl][2]) | ((uint32_t)f2bf(uacc[mi][ntl][3])<<16);
        int addr = (c*128 + r0*2) ^ ((c&7)<<4);
        uint2 w; w.x=lo; w.y=hi;
        *(uint2*)((char*)myUT + addr) = w;
      }

    /* issue w2b frag loads (vmcnt) BEFORE the lgkm-only sync: they fly under alpha@u */
    short8 bfw[4][4];
    #pragma unroll
    for (int ks=0;ks<4;++ks)
      #pragma unroll
      for (int ntl=0;ntl<4;++ntl)
        bfw[ks][ntl] = *(const short8*)(w2bp + (size_t)(((ks*8)+(4*h+ntl))*64 + lane)*8);
    float bvals[4];
    #pragma unroll
    for (int ntl=0;ntl<4;++ntl) bvals[ntl] = bias[16*(4*h+ntl) + l15];

    WAVE_SYNC();   /* uT (and alpha on h=0) visible wave-wide */

    /* oacc = bias + alpha@u + x@W2b */
    f32x4 oacc[4][4];
    #pragma unroll
    for (int ntl=0;ntl<4;++ntl){
      float b = bvals[ntl];
      #pragma unroll
      for (int mi=0;mi<4;++mi){ f32x4 v; v[0]=b; v[1]=b; v[2]=b; v[3]=b; oacc[mi][ntl]=v; }
    }
    #pragma unroll
    for (int ks2=0;ks2<2;++ks2){
      int kb = (32*ks2 + 8*g)*2;
      short8 afr[4], bfr[4];
      #pragma unroll
      for (int mi=0;mi<4;++mi){
        int i = 16*mi + l15;
        int addr = (i*128 + kb) ^ ((i&7)<<4);
        afr[mi] = *(const short8*)((char*)myALPHA + addr);
      }
      #pragma unroll
      for (int ntl=0;ntl<4;++ntl){
        int n = 16*ntl + l15;
        int addr = (n*128 + kb) ^ ((n&7)<<4);
        bfr[ntl] = *(const short8*)((char*)myUT + addr);
      }
      #pragma unroll
      for (int mi=0;mi<4;++mi)
        #pragma unroll
        for (int ntl=0;ntl<4;++ntl)
          oacc[mi][ntl] = __builtin_amdgcn_mfma_f32_16x16x32_bf16(afr[mi], bfr[ntl], oacc[mi][ntl], 0,0,0);
    }
    #pragma unroll
    for (int ks=0;ks<4;++ks)
      #pragma unroll
      for (int mi=0;mi<4;++mi)
        #pragma unroll
        for (int ntl=0;ntl<4;++ntl)
          oacc[mi][ntl] = __builtin_amdgcn_mfma_f32_16x16x32_bf16(xf[mi][ks], bfw[ks][ntl], oacc[mi][ntl], 0,0,0);

    /* ELU + predicated store of this feature half */
    #pragma unroll
    for (int mi=0;mi<4;++mi){
      #pragma unroll
      for (int q=0;q<4;++q){
        int r = 16*mi + 4*g + q;
        long grow = row_base + r;
        if (r < TILE_ROWS && grow < (long)ROWS_TOTAL){
          float* orow = out + grow*128 + 64*h;
          #pragma unroll
          for (int ntl=0;ntl<4;++ntl){
            float v = oacc[mi][ntl][q];
            v = v > 0.f ? v : (__expf(v) - 1.f);
            orow[16*ntl + l15] = v;
          }
        }
      }
    }
    WAVE_SYNC();   /* drain before next half overwrites myUT */
  }
}

extern "C" void kernel_launch(void* const* d_in, const int* in_sizes, int n_in,
                              void* d_out, int out_size, void* d_ws, size_t ws_size,
                              hipStream_t stream) {
  const float* x   = (const float*)d_in[0];
  const float* cam = (const float*)d_in[1];
  const float* W1  = (const float*)d_in[2];
  const float* a   = (const float*)d_in[3];
  const float* W2w = (const float*)d_in[4];
  const float* W2b = (const float*)d_in[5];
  float* out = (float*)d_out;

  char* ws = (char*)d_ws;
  uint16_t* Up   = (uint16_t*)(ws + 0);
  uint16_t* w2bp = (uint16_t*)(ws + 32768);
  uint16_t* stp  = (uint16_t*)(ws + 65536);

  pack_kernel<<<136, 256, 0, stream>>>(W1, W2w, a, Up, w2bp, stp);
  camgat_kernel<<<NWG, 64*WPG, 0, stream>>>(x, cam, W2b, Up, w2bp, stp, out);
}